// Round 3
// baseline (815.147 us; speedup 1.0000x reference)
//
#include <hip/hip_runtime.h>
#include <stdint.h>

// ---------------- types ----------------
typedef float   f32x4 __attribute__((ext_vector_type(4)));
typedef float   f32x2 __attribute__((ext_vector_type(2)));
typedef __bf16  bfx8  __attribute__((ext_vector_type(8)));
typedef uint16_t u16x8 __attribute__((ext_vector_type(8)));

#define AS1(p) ((__attribute__((address_space(1))) void*)(p))
#define AS3(p) ((__attribute__((address_space(3))) void*)(p))

__device__ __forceinline__ uint16_t f2bf(float f) {
    union { float f; uint32_t u; } c; c.f = f;
    uint32_t u = c.u;
    return (uint16_t)((u + 0x7FFFu + ((u >> 16) & 1u)) >> 16);
}
__device__ __forceinline__ float sigmoidf_(float x) { return 1.0f / (1.0f + __expf(-x)); }

// ---------------- weight convert+transpose: fp32 [K][N] -> bf16 [N][K] ----------------
// arena layout (uint16 units):
//   wqkv: [L][1536][512]   @ 0         (q rows 0..511, k 512..1023, v 1024..1535)
//   wo  : [L][512][512]    @ 4718592
//   w1  : [L][512][512]    @ 6291456
//   w2  : [L][512][512]    @ 7864320
//   wemb: [512][128]       @ 9437184
__global__ __launch_bounds__(256) void wconv_k(
    const float* __restrict__ Wq, const float* __restrict__ Wk, const float* __restrict__ Wv,
    const float* __restrict__ Wo, const float* __restrict__ W1, const float* __restrict__ W2,
    const float* __restrict__ Wemb, uint16_t* __restrict__ arena)
{
    __shared__ uint16_t tl[64][65];
    const int z = blockIdx.z;
    const float* in; uint16_t* out; int K, N;
    if (z < 36) {
        const int type = z / 6, l = z % 6;
        const float* bases[6] = {Wq, Wk, Wv, Wo, W1, W2};
        in = bases[type] + (size_t)l * 512 * 512;
        K = 512; N = 512;
        if (type < 3) out = arena + (size_t)l * 786432u + (size_t)type * 262144u;
        else          out = arena + 4718592u + (size_t)(type - 3) * 1572864u + (size_t)l * 262144u;
    } else {
        if (blockIdx.y >= 2) return;      // K=128 -> only 2 k-tiles
        in = Wemb; K = 128; N = 512;
        out = arena + 9437184u;
    }
    const int n0 = blockIdx.x * 64, k0 = blockIdx.y * 64;
    const int t = threadIdx.x, r = t >> 2, seg = t & 3;
    const float* src = in + (size_t)(k0 + r) * N + n0 + seg * 16;
#pragma unroll
    for (int v2 = 0; v2 < 4; ++v2) {
        f32x4 d = *(const f32x4*)(src + v2 * 4);
#pragma unroll
        for (int j = 0; j < 4; ++j) tl[r][seg * 16 + v2 * 4 + j] = f2bf(d[j]);
    }
    __syncthreads();
    u16x8 o0, o1;
#pragma unroll
    for (int j = 0; j < 8; ++j) { o0[j] = tl[seg * 16 + j][r]; o1[j] = tl[seg * 16 + 8 + j][r]; }
    uint16_t* dst = out + (size_t)(n0 + r) * K + k0 + seg * 16;
    *(u16x8*)dst = o0; *(u16x8*)(dst + 8) = o1;
}

// ---------------- mean over ensemble M=10: features [B,M,S,F] -> bf16 [T][F] ----------------
__global__ __launch_bounds__(256) void fmean_k(const float* __restrict__ feat, uint16_t* __restrict__ fm)
{
    int id = blockIdx.x * 256 + threadIdx.x;      // 0 .. 4096*128-1
    int f = id & 127, row = id >> 7;              // row = b*1024+s
    int b = row >> 10, s = row & 1023;
    float acc = 0.f;
#pragma unroll
    for (int m = 0; m < 10; ++m)
        acc += feat[(size_t)((b * 10 + m) * 1024 + s) * 128 + f];
    fm[id] = f2bf(acc * 0.1f);
}

// ---------------- station embedding add (+NaN check) ; writes x32 and x16 ----------------
__global__ __launch_bounds__(256) void station_k(const float* __restrict__ target,
    const float* __restrict__ semb, float* __restrict__ x32, uint16_t* __restrict__ x16)
{
    int row = blockIdx.x;               // b*1024+s
    int s = row & 1023;
    bool bad = false;
#pragma unroll
    for (int v = 0; v < 6; ++v) bad = bad || isnan(target[(size_t)row * 6 + v]);
    int sid = bad ? 1024 : s;
    const float* se = semb + (size_t)sid * 512;
    for (int c = threadIdx.x; c < 512; c += 256) {
        float val = x32[(size_t)row * 512 + c] + se[c];
        x32[(size_t)row * 512 + c] = val;
        x16[(size_t)row * 512 + c] = f2bf(val);
    }
}

// ---------------- bf16 MFMA GEMM 64x64 tile: C[M,N] = A[M,K] @ Bw^T  (Bw is [N][K]) ----------------
// BK=64, 4 waves (2x2 of 32x32), global_load_lds width-16 staging, linear LDS.
template<int BIAS, int SILU, int OUTBF>
__global__ __launch_bounds__(256) void gemm64(const uint16_t* __restrict__ A,
    const uint16_t* __restrict__ Bw, const float* __restrict__ bias,
    void* __restrict__ Cout, int Msz, int Nsz, int Ksz)
{
    __shared__ uint16_t lA[64 * 64];
    __shared__ uint16_t lB[64 * 64];
    const int t = threadIdx.x;
    const int lane = t & 63, w = t >> 6;
    const int wm = (w >> 1) * 32, wn = (w & 1) * 32;
    const int m0 = blockIdx.y * 64, n0 = blockIdx.x * 64;
    const int l15 = lane & 15, l4 = lane >> 4;
    char* lAb = (char*)lA; char* lBb = (char*)lB;
    const int srow = lane >> 3, sseg = lane & 7;      // staging: 8 rows x 8 segs of 16B per wave-instr
    f32x4 acc[2][2] = {};
    for (int k0 = 0; k0 < Ksz; k0 += 64) {
#pragma unroll
        for (int i = 0; i < 2; ++i) {
            int row = w * 16 + i * 8 + srow;
            const char* ga = (const char*)A + ((size_t)(m0 + row) * Ksz + k0) * 2 + sseg * 16;
            __builtin_amdgcn_global_load_lds(AS1(ga), AS3(lAb + (w * 16 + i * 8) * 128), 16, 0, 0);
            const char* gb = (const char*)Bw + ((size_t)(n0 + row) * Ksz + k0) * 2 + sseg * 16;
            __builtin_amdgcn_global_load_lds(AS1(gb), AS3(lBb + (w * 16 + i * 8) * 128), 16, 0, 0);
        }
        __syncthreads();
#pragma unroll
        for (int kf = 0; kf < 2; ++kf) {
            bfx8 af[2], bf2[2];
#pragma unroll
            for (int mf = 0; mf < 2; ++mf)
                af[mf] = *(const bfx8*)(lAb + (wm + mf * 16 + l15) * 128 + kf * 64 + l4 * 16);
#pragma unroll
            for (int nf = 0; nf < 2; ++nf)
                bf2[nf] = *(const bfx8*)(lBb + (wn + nf * 16 + l15) * 128 + kf * 64 + l4 * 16);
#pragma unroll
            for (int mf = 0; mf < 2; ++mf)
#pragma unroll
                for (int nf = 0; nf < 2; ++nf)
                    acc[mf][nf] = __builtin_amdgcn_mfma_f32_16x16x32_bf16(af[mf], bf2[nf], acc[mf][nf], 0, 0, 0);
        }
        __syncthreads();
    }
#pragma unroll
    for (int mf = 0; mf < 2; ++mf)
#pragma unroll
        for (int nf = 0; nf < 2; ++nf)
#pragma unroll
            for (int r = 0; r < 4; ++r) {
                int row = m0 + wm + mf * 16 + l4 * 4 + r;
                int col = n0 + wn + nf * 16 + l15;
                float v = acc[mf][nf][r];
                if (BIAS) v += bias[col];
                if (SILU) v = v * sigmoidf_(v);
                if (OUTBF) ((uint16_t*)Cout)[(size_t)row * Nsz + col] = f2bf(v);
                else       ((float*)Cout)[(size_t)row * Nsz + col] = v;
            }
}

// ---------------- bf16 MFMA GEMM 128x128 tile (m97 structure): for the qkv GEMM ----------------
// BK=64, 4 waves (2x2 of 64x64 = 4x4 fragments each), global_load_lds staging, linear LDS.
__global__ __launch_bounds__(256) void gemm128(const uint16_t* __restrict__ A,
    const uint16_t* __restrict__ Bw, uint16_t* __restrict__ Cout, int Nsz, int Ksz)
{
    __shared__ uint16_t lA[128 * 64];
    __shared__ uint16_t lB[128 * 64];
    const int t = threadIdx.x;
    const int lane = t & 63, w = t >> 6;
    const int wm = (w >> 1) * 64, wn = (w & 1) * 64;
    const int m0 = blockIdx.y * 128, n0 = blockIdx.x * 128;
    const int l15 = lane & 15, l4 = lane >> 4;
    char* lAb = (char*)lA; char* lBb = (char*)lB;
    const int srow = lane >> 3, sseg = lane & 7;
    f32x4 acc[4][4] = {};
    for (int k0 = 0; k0 < Ksz; k0 += 64) {
#pragma unroll
        for (int i = 0; i < 4; ++i) {
            int row = w * 32 + i * 8 + srow;
            const char* ga = (const char*)A + ((size_t)(m0 + row) * Ksz + k0) * 2 + sseg * 16;
            __builtin_amdgcn_global_load_lds(AS1(ga), AS3(lAb + (w * 32 + i * 8) * 128), 16, 0, 0);
            const char* gb = (const char*)Bw + ((size_t)(n0 + row) * Ksz + k0) * 2 + sseg * 16;
            __builtin_amdgcn_global_load_lds(AS1(gb), AS3(lBb + (w * 32 + i * 8) * 128), 16, 0, 0);
        }
        __syncthreads();
#pragma unroll
        for (int kf = 0; kf < 2; ++kf) {
            bfx8 af[4], bf2[4];
#pragma unroll
            for (int mf = 0; mf < 4; ++mf)
                af[mf] = *(const bfx8*)(lAb + (wm + mf * 16 + l15) * 128 + kf * 64 + l4 * 16);
#pragma unroll
            for (int nf = 0; nf < 4; ++nf)
                bf2[nf] = *(const bfx8*)(lBb + (wn + nf * 16 + l15) * 128 + kf * 64 + l4 * 16);
#pragma unroll
            for (int mf = 0; mf < 4; ++mf)
#pragma unroll
                for (int nf = 0; nf < 4; ++nf)
                    acc[mf][nf] = __builtin_amdgcn_mfma_f32_16x16x32_bf16(af[mf], bf2[nf], acc[mf][nf], 0, 0, 0);
        }
        __syncthreads();
    }
#pragma unroll
    for (int mf = 0; mf < 4; ++mf)
#pragma unroll
        for (int nf = 0; nf < 4; ++nf)
#pragma unroll
            for (int r = 0; r < 4; ++r) {
                int row = m0 + wm + mf * 16 + l4 * 4 + r;
                int col = n0 + wn + nf * 16 + l15;
                Cout[(size_t)row * Nsz + col] = f2bf(acc[mf][nf][r]);
            }
}

// ---------------- V transpose: qkv v-block [b][s][h*64+dh] -> vt [b][h][dh][S] ----------------
__global__ __launch_bounds__(256) void vtrans_k(const uint16_t* __restrict__ qkv, uint16_t* __restrict__ vt)
{
    __shared__ uint16_t tl[64][65];
    const int bh = blockIdx.y;           // b*8+h
    const int s0 = blockIdx.x * 64;
    const int b = bh >> 3, h = bh & 7;
    const int t = threadIdx.x, r = t >> 2, seg = t & 3;
    const uint16_t* src = qkv + (size_t)(b * 1024 + s0 + r) * 1536 + 1024 + h * 64 + seg * 16;
    u16x8 a0 = *(const u16x8*)src;
    u16x8 a1 = *(const u16x8*)(src + 8);
#pragma unroll
    for (int j = 0; j < 8; ++j) { tl[r][seg * 16 + j] = a0[j]; tl[r][seg * 16 + 8 + j] = a1[j]; }
    __syncthreads();
    u16x8 o0, o1;
#pragma unroll
    for (int j = 0; j < 8; ++j) { o0[j] = tl[seg * 16 + j][r]; o1[j] = tl[seg * 16 + 8 + j][r]; }
    uint16_t* dst = vt + (size_t)(bh * 64 + r) * 1024 + s0 + seg * 16;
    *(u16x8*)dst = o0; *(u16x8*)(dst + 8) = o1;
}

// ---------------- fused attention: softmax over BATCH dim (elementwise in q,k) ----------------
// grid 512 (h = bid&7 -> one head per XCD), block = 512 threads = 8 waves:
// wave w -> batch b = w&3, k-group g = w>>2. QBLK=16; groups interleave 32-wide
// k-tiles and combine partial O via LDS.
__global__ __launch_bounds__(512) void attn_k(const uint16_t* __restrict__ qkv,
    const uint16_t* __restrict__ vt, uint16_t* __restrict__ o16)
{
    __shared__ float    sS[2][4][16][33];   // [g][b][q][k]
    __shared__ uint16_t sP[2][4][16][32];
    __shared__ float    sO[4][16][64];
    const int t = threadIdx.x;
    const int lane = t & 63, w = t >> 6;
    const int b = w & 3, g = w >> 2;
    const int h  = blockIdx.x & 7;
    const int q0 = (blockIdx.x >> 3) * 16;
    const int l15 = lane & 15, l4 = lane >> 4;

    bfx8 qa[2];
#pragma unroll
    for (int kf = 0; kf < 2; ++kf)
        qa[kf] = *(const bfx8*)(qkv + (size_t)(b * 1024 + q0 + l15) * 1536 + h * 64 + kf * 32 + l4 * 8);

    f32x4 oacc[4] = {};
    for (int it = 0; it < 16; ++it) {
        const int k0 = (it * 2 + g) * 32;
        f32x4 sacc[2] = {};
        bfx8 kb[2][2];
#pragma unroll
        for (int nf = 0; nf < 2; ++nf)
#pragma unroll
            for (int kf = 0; kf < 2; ++kf)
                kb[nf][kf] = *(const bfx8*)(qkv + (size_t)(b * 1024 + k0 + nf * 16 + l15) * 1536 + 512 + h * 64 + kf * 32 + l4 * 8);
#pragma unroll
        for (int kf = 0; kf < 2; ++kf)
#pragma unroll
            for (int nf = 0; nf < 2; ++nf)
                sacc[nf] = __builtin_amdgcn_mfma_f32_16x16x32_bf16(qa[kf], kb[nf][kf], sacc[nf], 0, 0, 0);
#pragma unroll
        for (int nf = 0; nf < 2; ++nf)
#pragma unroll
            for (int r = 0; r < 4; ++r)
                sS[g][b][l4 * 4 + r][nf * 16 + l15] = sacc[nf][r] * 0.125f;
        __syncthreads();
#pragma unroll
        for (int jj = 0; jj < 2; ++jj) {
            int e = jj * 512 + t;
            int g2 = e >> 9, qk = e & 511;
            int qi = qk >> 5, ki = qk & 31;
            float s0v = sS[g2][0][qi][ki], s1v = sS[g2][1][qi][ki];
            float s2v = sS[g2][2][qi][ki], s3v = sS[g2][3][qi][ki];
            float mx = fmaxf(fmaxf(s0v, s1v), fmaxf(s2v, s3v));
            float e0 = __expf(s0v - mx), e1 = __expf(s1v - mx);
            float e2 = __expf(s2v - mx), e3 = __expf(s3v - mx);
            float inv = 1.0f / (e0 + e1 + e2 + e3);
            sP[g2][0][qi][ki] = f2bf(e0 * inv);
            sP[g2][1][qi][ki] = f2bf(e1 * inv);
            sP[g2][2][qi][ki] = f2bf(e2 * inv);
            sP[g2][3][qi][ki] = f2bf(e3 * inv);
        }
        __syncthreads();
        bfx8 pa = *(const bfx8*)(&sP[g][b][l15][l4 * 8]);
        bfx8 vb[4];
#pragma unroll
        for (int nf = 0; nf < 4; ++nf)
            vb[nf] = *(const bfx8*)(vt + (size_t)((b * 8 + h) * 64 + nf * 16 + l15) * 1024 + k0 + l4 * 8);
#pragma unroll
        for (int nf = 0; nf < 4; ++nf)
            oacc[nf] = __builtin_amdgcn_mfma_f32_16x16x32_bf16(pa, vb[nf], oacc[nf], 0, 0, 0);
    }
    if (g == 1) {
#pragma unroll
        for (int nf = 0; nf < 4; ++nf)
#pragma unroll
            for (int r = 0; r < 4; ++r)
                sO[b][l4 * 4 + r][nf * 16 + l15] = oacc[nf][r];
    }
    __syncthreads();
    if (g == 0) {
#pragma unroll
        for (int nf = 0; nf < 4; ++nf)
#pragma unroll
            for (int r = 0; r < 4; ++r) {
                float v = oacc[nf][r] + sO[b][l4 * 4 + r][nf * 16 + l15];
                o16[(size_t)(b * 1024 + q0 + l4 * 4 + r) * 512 + h * 64 + nf * 16 + l15] = f2bf(v);
            }
    }
}

// ---------------- fused  ln_attn -> silu -> ln1  (one wave per row) ----------------
__global__ __launch_bounds__(64) void ln_fuse_k(const float* __restrict__ in,
    const float* __restrict__ g1, const float* __restrict__ b1,
    const float* __restrict__ g2, const float* __restrict__ b2,
    float* __restrict__ h32, uint16_t* __restrict__ h16)
{
    const int row = blockIdx.x, lane = threadIdx.x;
    const float* p = in + (size_t)row * 512 + lane * 8;
    f32x4 a = *(const f32x4*)p, bvec = *(const f32x4*)(p + 4);
    float x[8] = {a[0], a[1], a[2], a[3], bvec[0], bvec[1], bvec[2], bvec[3]};
    float sum = 0.f, sq = 0.f;
#pragma unroll
    for (int i = 0; i < 8; ++i) { sum += x[i]; sq += x[i] * x[i]; }
    for (int m = 32; m; m >>= 1) { sum += __shfl_xor(sum, m); sq += __shfl_xor(sq, m); }
    float mu = sum * (1.f / 512.f);
    float rs = rsqrtf(sq * (1.f / 512.f) - mu * mu + 1e-5f);
    float y[8]; float s2 = 0.f, q2 = 0.f;
#pragma unroll
    for (int i = 0; i < 8; ++i) {
        int c = lane * 8 + i;
        float v = (x[i] - mu) * rs * g1[c] + b1[c];
        v = v * sigmoidf_(v);
        y[i] = v; s2 += v; q2 += v * v;
    }
    for (int m = 32; m; m >>= 1) { s2 += __shfl_xor(s2, m); q2 += __shfl_xor(q2, m); }
    float mu2 = s2 * (1.f / 512.f);
    float rs2 = rsqrtf(q2 * (1.f / 512.f) - mu2 * mu2 + 1e-5f);
#pragma unroll
    for (int i = 0; i < 8; ++i) {
        int c = lane * 8 + i;
        float v = (y[i] - mu2) * rs2 * g2[c] + b2[c];
        h32[(size_t)row * 512 + c] = v;
        h16[(size_t)row * 512 + c] = f2bf(v);
    }
}

// ---------------- x = ln2(f + h) ----------------
__global__ __launch_bounds__(64) void ln_res_k(const float* __restrict__ f, const float* __restrict__ hres,
    const float* __restrict__ g, const float* __restrict__ bb,
    float* __restrict__ x32, uint16_t* __restrict__ x16)
{
    const int row = blockIdx.x, lane = threadIdx.x;
    const size_t base = (size_t)row * 512 + lane * 8;
    f32x4 a = *(const f32x4*)(f + base), b2v = *(const f32x4*)(f + base + 4);
    f32x4 ha = *(const f32x4*)(hres + base), hb = *(const f32x4*)(hres + base + 4);
    float x[8] = {a[0] + ha[0], a[1] + ha[1], a[2] + ha[2], a[3] + ha[3],
                  b2v[0] + hb[0], b2v[1] + hb[1], b2v[2] + hb[2], b2v[3] + hb[3]};
    float sum = 0.f, sq = 0.f;
#pragma unroll
    for (int i = 0; i < 8; ++i) { sum += x[i]; sq += x[i] * x[i]; }
    for (int m = 32; m; m >>= 1) { sum += __shfl_xor(sum, m); sq += __shfl_xor(sq, m); }
    float mu = sum * (1.f / 512.f);
    float rs = rsqrtf(sq * (1.f / 512.f) - mu * mu + 1e-5f);
#pragma unroll
    for (int i = 0; i < 8; ++i) {
        int c = lane * 8 + i;
        float v = (x[i] - mu) * rs * g[c] + bb[c];
        x32[base + i] = v;
        x16[base + i] = f2bf(v);
    }
}

// ---------------- regression head: [T,512] @ [512,18] + b ----------------
// 8 lanes per row, each lane covers a 64-wide K chunk; fp32 FMA into acc[18];
// 3-stage shfl_xor reduce within the 8-lane group. 128 blocks x 256 threads.
__global__ __launch_bounds__(256) void reg_k(const float* __restrict__ x, const float* __restrict__ W,
    const float* __restrict__ bb, float* __restrict__ out)
{
    const int gid = blockIdx.x * 256 + threadIdx.x;
    const int row = gid >> 3, kq = gid & 7;
    const float* xp = x + (size_t)row * 512 + kq * 64;
    float acc[18];
#pragma unroll
    for (int j = 0; j < 18; ++j) acc[j] = 0.f;
    for (int k0 = 0; k0 < 64; k0 += 4) {
        f32x4 xv = *(const f32x4*)(xp + k0);
#pragma unroll
        for (int kk = 0; kk < 4; ++kk) {
            const float* wr = W + (size_t)(kq * 64 + k0 + kk) * 18;
            f32x4 w0 = *(const f32x4*)(wr);
            f32x4 w1 = *(const f32x4*)(wr + 4);
            f32x4 w2 = *(const f32x4*)(wr + 8);
            f32x4 w3 = *(const f32x4*)(wr + 12);
            f32x2 w4 = *(const f32x2*)(wr + 16);
            float xs = xv[kk];
#pragma unroll
            for (int j = 0; j < 4; ++j) acc[j] += xs * w0[j];
#pragma unroll
            for (int j = 0; j < 4; ++j) acc[4 + j] += xs * w1[j];
#pragma unroll
            for (int j = 0; j < 4; ++j) acc[8 + j] += xs * w2[j];
#pragma unroll
            for (int j = 0; j < 4; ++j) acc[12 + j] += xs * w3[j];
            acc[16] += xs * w4[0];
            acc[17] += xs * w4[1];
        }
    }
#pragma unroll
    for (int j = 0; j < 18; ++j) {
        acc[j] += __shfl_xor(acc[j], 1);
        acc[j] += __shfl_xor(acc[j], 2);
        acc[j] += __shfl_xor(acc[j], 4);
    }
    if (kq == 0) {
#pragma unroll
        for (int j = 0; j < 18; ++j)
            out[(size_t)row * 18 + j] = acc[j] + bb[j];
    }
}

// ---------------- launch ----------------
extern "C" void kernel_launch(void* const* d_in, const int* in_sizes, int n_in,
                              void* d_out, int out_size, void* d_ws, size_t ws_size,
                              hipStream_t stream)
{
    const float* features = (const float*)d_in[0];
    const float* target   = (const float*)d_in[1];
    const float* emb_W    = (const float*)d_in[4];
    const float* emb_b    = (const float*)d_in[5];
    const float* station  = (const float*)d_in[6];
    const float* Wq   = (const float*)d_in[7];
    const float* Wk   = (const float*)d_in[8];
    const float* Wv   = (const float*)d_in[9];
    const float* Wo   = (const float*)d_in[10];
    const float* attn_b = (const float*)d_in[11];
    const float* lng  = (const float*)d_in[12];
    const float* lnb  = (const float*)d_in[13];
    const float* W1   = (const float*)d_in[14];
    const float* b1   = (const float*)d_in[15];
    const float* W2   = (const float*)d_in[16];
    const float* b2   = (const float*)d_in[17];
    const float* ln1g = (const float*)d_in[18];
    const float* ln1b = (const float*)d_in[19];
    const float* ln2g = (const float*)d_in[20];
    const float* ln2b = (const float*)d_in[21];
    const float* regW = (const float*)d_in[22];
    const float* regb = (const float*)d_in[23];
    float* out = (float*)d_out;

    const size_t NEEDED = 78774272;
    if (ws_size < NEEDED) return;   // fail visibly (output stays poisoned) rather than corrupt

    char* ws = (char*)d_ws;
    uint16_t* wt   = (uint16_t*)(ws);             // 19,005,440 B bf16 weight arena
    float*    x32  = (float*)(ws + 19005440);     // 8 MB
    uint16_t* x16  = (uint16_t*)(ws + 27394048);  // 4 MB
    uint16_t* qkv  = (uint16_t*)(ws + 31588352);  // 12 MB
    uint16_t* vt   = (uint16_t*)(ws + 44171264);  // 4 MB
    uint16_t* o16  = (uint16_t*)(ws + 48365568);  // 4 MB
    float*    t32  = (float*)(ws + 52559872);     // 8 MB
    float*    h32  = (float*)(ws + 60948480);     // 8 MB
    uint16_t* h16  = (uint16_t*)(ws + 69337088);  // 4 MB
    uint16_t* f16  = (uint16_t*)(ws + 73531392);  // 4 MB
    uint16_t* fm16 = (uint16_t*)(ws + 77725696);  // 1 MB

    wconv_k<<<dim3(8, 8, 37), 256, 0, stream>>>(Wq, Wk, Wv, Wo, W1, W2, emb_W, wt);
    fmean_k<<<dim3(2048), 256, 0, stream>>>(features, fm16);
    gemm64<1, 0, 0><<<dim3(8, 64), 256, 0, stream>>>(fm16, wt + 9437184u, emb_b, x32, 4096, 512, 128);
    station_k<<<dim3(4096), 256, 0, stream>>>(target, station, x32, x16);

    for (int l = 0; l < 6; ++l) {
        gemm128<<<dim3(12, 32), 256, 0, stream>>>(x16, wt + (size_t)l * 786432u, qkv, 1536, 512);
        vtrans_k<<<dim3(16, 32), 256, 0, stream>>>(qkv, vt);
        attn_k<<<dim3(512), 512, 0, stream>>>(qkv, vt, o16);
        gemm64<1, 0, 0><<<dim3(8, 64), 256, 0, stream>>>(o16, wt + 4718592u + (size_t)l * 262144u, attn_b + l * 512, t32, 4096, 512, 512);
        ln_fuse_k<<<dim3(4096), 64, 0, stream>>>(t32, lng + l * 512, lnb + l * 512, ln1g + l * 512, ln1b + l * 512, h32, h16);
        gemm64<1, 1, 1><<<dim3(8, 64), 256, 0, stream>>>(h16, wt + 6291456u + (size_t)l * 262144u, b1 + l * 512, f16, 4096, 512, 512);
        gemm64<1, 0, 0><<<dim3(8, 64), 256, 0, stream>>>(f16, wt + 7864320u + (size_t)l * 262144u, b2 + l * 512, t32, 4096, 512, 512);
        ln_res_k<<<dim3(4096), 64, 0, stream>>>(t32, h32, ln2g + l * 512, ln2b + l * 512, x32, x16);
    }
    reg_k<<<dim3(128), 256, 0, stream>>>(x32, regW, regb, out);
}

// Round 5
// 687.289 us; speedup vs baseline: 1.1860x; 1.1860x over previous
//
#include <hip/hip_runtime.h>
#include <stdint.h>

// ---------------- types ----------------
typedef float   f32x4 __attribute__((ext_vector_type(4)));
typedef float   f32x2 __attribute__((ext_vector_type(2)));
typedef __bf16  bfx8  __attribute__((ext_vector_type(8)));
typedef uint16_t u16x8 __attribute__((ext_vector_type(8)));

#define AS1(p) ((__attribute__((address_space(1))) void*)(p))
#define AS3(p) ((__attribute__((address_space(3))) void*)(p))

__device__ __forceinline__ uint16_t f2bf(float f) {
    union { float f; uint32_t u; } c; c.f = f;
    uint32_t u = c.u;
    return (uint16_t)((u + 0x7FFFu + ((u >> 16) & 1u)) >> 16);
}
__device__ __forceinline__ float bf2f(uint16_t v) {
    union { uint32_t u; float f; } c; c.u = ((uint32_t)v) << 16; return c.f;
}
__device__ __forceinline__ float sigmoidf_(float x) { return 1.0f / (1.0f + __expf(-x)); }
__device__ __forceinline__ float frcp(float x) { float r; asm("v_rcp_f32 %0, %1" : "=v"(r) : "v"(x)); return r; }
// LDS-only barrier: drains ds ops but leaves global (vmcnt) loads in flight.
__device__ __forceinline__ void bar_lds() {
    asm volatile("s_waitcnt lgkmcnt(0)" ::: "memory");
    __builtin_amdgcn_s_barrier();
}

// ---------------- weight convert+transpose: fp32 [K][N] -> bf16 [N][K] ----------------
// arena layout (uint16 units):
//   wqkv: [L][1536][512]   @ 0         (q rows 0..511, k 512..1023, v 1024..1535)
//   wo  : [L][512][512]    @ 4718592
//   w1  : [L][512][512]    @ 6291456
//   w2  : [L][512][512]    @ 7864320
//   wemb: [512][128]       @ 9437184
__global__ __launch_bounds__(256) void wconv_k(
    const float* __restrict__ Wq, const float* __restrict__ Wk, const float* __restrict__ Wv,
    const float* __restrict__ Wo, const float* __restrict__ W1, const float* __restrict__ W2,
    const float* __restrict__ Wemb, uint16_t* __restrict__ arena)
{
    __shared__ uint16_t tl[64][65];
    const int z = blockIdx.z;
    const float* in; uint16_t* out; int K, N;
    if (z < 36) {
        const int type = z / 6, l = z % 6;
        const float* bases[6] = {Wq, Wk, Wv, Wo, W1, W2};
        in = bases[type] + (size_t)l * 512 * 512;
        K = 512; N = 512;
        if (type < 3) out = arena + (size_t)l * 786432u + (size_t)type * 262144u;
        else          out = arena + 4718592u + (size_t)(type - 3) * 1572864u + (size_t)l * 262144u;
    } else {
        if (blockIdx.y >= 2) return;      // K=128 -> only 2 k-tiles
        in = Wemb; K = 128; N = 512;
        out = arena + 9437184u;
    }
    const int n0 = blockIdx.x * 64, k0 = blockIdx.y * 64;
    const int t = threadIdx.x, r = t >> 2, seg = t & 3;
    const float* src = in + (size_t)(k0 + r) * N + n0 + seg * 16;
#pragma unroll
    for (int v2 = 0; v2 < 4; ++v2) {
        f32x4 d = *(const f32x4*)(src + v2 * 4);
#pragma unroll
        for (int j = 0; j < 4; ++j) tl[r][seg * 16 + v2 * 4 + j] = f2bf(d[j]);
    }
    __syncthreads();
    u16x8 o0, o1;
#pragma unroll
    for (int j = 0; j < 8; ++j) { o0[j] = tl[seg * 16 + j][r]; o1[j] = tl[seg * 16 + 8 + j][r]; }
    uint16_t* dst = out + (size_t)(n0 + r) * K + k0 + seg * 16;
    *(u16x8*)dst = o0; *(u16x8*)(dst + 8) = o1;
}

// ---------------- mean over ensemble M=10: features [B,M,S,F] -> bf16 [T][F] ----------------
__global__ __launch_bounds__(256) void fmean_k(const float* __restrict__ feat, uint16_t* __restrict__ fm)
{
    int id = blockIdx.x * 256 + threadIdx.x;      // 0 .. 4096*128-1
    int f = id & 127, row = id >> 7;              // row = b*1024+s
    int b = row >> 10, s = row & 1023;
    float acc = 0.f;
#pragma unroll
    for (int m = 0; m < 10; ++m)
        acc += feat[(size_t)((b * 10 + m) * 1024 + s) * 128 + f];
    fm[id] = f2bf(acc * 0.1f);
}

// ---------------- station embedding add (+NaN check): x16 = emb32 + station ----------------
__global__ __launch_bounds__(256) void station_k(const float* __restrict__ target,
    const float* __restrict__ semb, const float* __restrict__ emb32, uint16_t* __restrict__ x16)
{
    int row = blockIdx.x;               // b*1024+s
    int s = row & 1023;
    bool bad = false;
#pragma unroll
    for (int v = 0; v < 6; ++v) bad = bad || isnan(target[(size_t)row * 6 + v]);
    int sid = bad ? 1024 : s;
    const float* se = semb + (size_t)sid * 512;
    for (int c = threadIdx.x; c < 512; c += 256) {
        float val = emb32[(size_t)row * 512 + c] + se[c];
        x16[(size_t)row * 512 + c] = f2bf(val);
    }
}

// ---------------- bf16 MFMA GEMM 64x64 tile: C[M,N] = A[M,K] @ Bw^T ----------------
// Bw is [N][Kb] with Kb = KMOD ? 512 : Ksz (KMOD: logical K wraps mod 512 -> Wo reuse
// for the split-O attention output by linearity). global_load_lds width-16 staging.
template<int BIAS, int SILU, int OUTBF, int KMOD>
__global__ __launch_bounds__(256) void gemm64(const uint16_t* __restrict__ A,
    const uint16_t* __restrict__ Bw, const float* __restrict__ bias,
    void* __restrict__ Cout, int Msz, int Nsz, int Ksz)
{
    __shared__ uint16_t lA[64 * 64];
    __shared__ uint16_t lB[64 * 64];
    const int t = threadIdx.x;
    const int lane = t & 63, w = t >> 6;
    const int wm = (w >> 1) * 32, wn = (w & 1) * 32;
    const int m0 = blockIdx.y * 64, n0 = blockIdx.x * 64;
    const int l15 = lane & 15, l4 = lane >> 4;
    char* lAb = (char*)lA; char* lBb = (char*)lB;
    const int srow = lane >> 3, sseg = lane & 7;      // staging: 8 rows x 8 segs of 16B per wave-instr
    f32x4 acc[2][2] = {};
    for (int k0 = 0; k0 < Ksz; k0 += 64) {
        const size_t bstride = KMOD ? 512 : (size_t)Ksz;
        const int bk0 = KMOD ? (k0 & 511) : k0;
#pragma unroll
        for (int i = 0; i < 2; ++i) {
            int row = w * 16 + i * 8 + srow;
            const char* ga = (const char*)A + ((size_t)(m0 + row) * Ksz + k0) * 2 + sseg * 16;
            __builtin_amdgcn_global_load_lds(AS1(ga), AS3(lAb + (w * 16 + i * 8) * 128), 16, 0, 0);
            const char* gb = (const char*)Bw + ((size_t)(n0 + row) * bstride + bk0) * 2 + sseg * 16;
            __builtin_amdgcn_global_load_lds(AS1(gb), AS3(lBb + (w * 16 + i * 8) * 128), 16, 0, 0);
        }
        __syncthreads();
#pragma unroll
        for (int kf = 0; kf < 2; ++kf) {
            bfx8 af[2], bf2[2];
#pragma unroll
            for (int mf = 0; mf < 2; ++mf)
                af[mf] = *(const bfx8*)(lAb + (wm + mf * 16 + l15) * 128 + kf * 64 + l4 * 16);
#pragma unroll
            for (int nf = 0; nf < 2; ++nf)
                bf2[nf] = *(const bfx8*)(lBb + (wn + nf * 16 + l15) * 128 + kf * 64 + l4 * 16);
#pragma unroll
            for (int mf = 0; mf < 2; ++mf)
#pragma unroll
                for (int nf = 0; nf < 2; ++nf)
                    acc[mf][nf] = __builtin_amdgcn_mfma_f32_16x16x32_bf16(af[mf], bf2[nf], acc[mf][nf], 0, 0, 0);
        }
        __syncthreads();
    }
#pragma unroll
    for (int mf = 0; mf < 2; ++mf)
#pragma unroll
        for (int nf = 0; nf < 2; ++nf)
#pragma unroll
            for (int r = 0; r < 4; ++r) {
                int row = m0 + wm + mf * 16 + l4 * 4 + r;
                int col = n0 + wn + nf * 16 + l15;
                float v = acc[mf][nf][r];
                if (BIAS) v += bias[col];
                if (SILU) v = v * sigmoidf_(v);
                if (OUTBF) ((uint16_t*)Cout)[(size_t)row * Nsz + col] = f2bf(v);
                else       ((float*)Cout)[(size_t)row * Nsz + col] = v;
            }
}

// ---------------- bf16 MFMA GEMM 128x128 tile (m97 structure): for the qkv GEMM ----------------
__global__ __launch_bounds__(256) void gemm128(const uint16_t* __restrict__ A,
    const uint16_t* __restrict__ Bw, uint16_t* __restrict__ Cout, int Nsz, int Ksz)
{
    __shared__ uint16_t lA[128 * 64];
    __shared__ uint16_t lB[128 * 64];
    const int t = threadIdx.x;
    const int lane = t & 63, w = t >> 6;
    const int wm = (w >> 1) * 64, wn = (w & 1) * 64;
    const int m0 = blockIdx.y * 128, n0 = blockIdx.x * 128;
    const int l15 = lane & 15, l4 = lane >> 4;
    char* lAb = (char*)lA; char* lBb = (char*)lB;
    const int srow = lane >> 3, sseg = lane & 7;
    f32x4 acc[4][4] = {};
    for (int k0 = 0; k0 < Ksz; k0 += 64) {
#pragma unroll
        for (int i = 0; i < 4; ++i) {
            int row = w * 32 + i * 8 + srow;
            const char* ga = (const char*)A + ((size_t)(m0 + row) * Ksz + k0) * 2 + sseg * 16;
            __builtin_amdgcn_global_load_lds(AS1(ga), AS3(lAb + (w * 32 + i * 8) * 128), 16, 0, 0);
            const char* gb = (const char*)Bw + ((size_t)(n0 + row) * Ksz + k0) * 2 + sseg * 16;
            __builtin_amdgcn_global_load_lds(AS1(gb), AS3(lBb + (w * 32 + i * 8) * 128), 16, 0, 0);
        }
        __syncthreads();
#pragma unroll
        for (int kf = 0; kf < 2; ++kf) {
            bfx8 af[4], bf2[4];
#pragma unroll
            for (int mf = 0; mf < 4; ++mf)
                af[mf] = *(const bfx8*)(lAb + (wm + mf * 16 + l15) * 128 + kf * 64 + l4 * 16);
#pragma unroll
            for (int nf = 0; nf < 4; ++nf)
                bf2[nf] = *(const bfx8*)(lBb + (wn + nf * 16 + l15) * 128 + kf * 64 + l4 * 16);
#pragma unroll
            for (int mf = 0; mf < 4; ++mf)
#pragma unroll
                for (int nf = 0; nf < 4; ++nf)
                    acc[mf][nf] = __builtin_amdgcn_mfma_f32_16x16x32_bf16(af[mf], bf2[nf], acc[mf][nf], 0, 0, 0);
        }
        __syncthreads();
    }
#pragma unroll
    for (int mf = 0; mf < 4; ++mf)
#pragma unroll
        for (int nf = 0; nf < 4; ++nf)
#pragma unroll
            for (int r = 0; r < 4; ++r) {
                int row = m0 + wm + mf * 16 + l4 * 4 + r;
                int col = n0 + wn + nf * 16 + l15;
                Cout[(size_t)row * Nsz + col] = f2bf(acc[mf][nf][r]);
            }
}

// ---------------- V transpose: qkv v-block [b][s][h*64+dh] -> vt [b][h][dh][S] ----------------
__global__ __launch_bounds__(256) void vtrans_k(const uint16_t* __restrict__ qkv, uint16_t* __restrict__ vt)
{
    __shared__ uint16_t tl[64][65];
    const int bh = blockIdx.y;           // b*8+h
    const int s0 = blockIdx.x * 64;
    const int b = bh >> 3, h = bh & 7;
    const int t = threadIdx.x, r = t >> 2, seg = t & 3;
    const uint16_t* src = qkv + (size_t)(b * 1024 + s0 + r) * 1536 + 1024 + h * 64 + seg * 16;
    u16x8 a0 = *(const u16x8*)src;
    u16x8 a1 = *(const u16x8*)(src + 8);
#pragma unroll
    for (int j = 0; j < 8; ++j) { tl[r][seg * 16 + j] = a0[j]; tl[r][seg * 16 + 8 + j] = a1[j]; }
    __syncthreads();
    u16x8 o0, o1;
#pragma unroll
    for (int j = 0; j < 8; ++j) { o0[j] = tl[seg * 16 + j][r]; o1[j] = tl[seg * 16 + 8 + j][r]; }
    uint16_t* dst = vt + (size_t)(bh * 64 + r) * 1024 + s0 + seg * 16;
    *(u16x8*)dst = o0; *(u16x8*)(dst + 8) = o1;
}

// ---------------- fused attention: softmax over BATCH dim (elementwise in q,k) ----------------
// QBLK=32, 8 waves = 4 batches x 2 k-groups; k-range split over 2 blocks (ks), partial
// O written to o16 [4096][1024] (combined later by the K=1024 o-proj GEMM, linearity).
// grid 512: h = bid&7 (head per XCD), qt = (bid>>3)&31, ks = bid>>8.
// lgkm-only barriers keep V/K global loads in flight across sync points.
// LDS P layout (byte offset from sPb): b*4096 + kg*2048 + ((q*64 + k*2) ^ ((q&3)<<4)).
__global__ __launch_bounds__(512, 4) void attn_k(const uint16_t* __restrict__ qkv,
    const uint16_t* __restrict__ vt, uint16_t* __restrict__ o16)
{
    __shared__ __align__(16) char smem[33792 + 16384];
    float*    sS  = (float*)smem;                 // [b][kg][32][33] f32 (33792 B)
    uint16_t* sPb = (uint16_t*)(smem + 33792);    // [b][kg] 2048B tiles, XOR-swizzled
    float*    sO  = (float*)smem;                 // alias (post-loop combine) [b][32][64]

    const int t = threadIdx.x;
    const int lane = t & 63, w = t >> 6;
    const int b = w & 3, kg = w >> 2;
    const int bid = blockIdx.x;
    const int h = bid & 7, qt = (bid >> 3) & 31, ks = bid >> 8;
    const int q0 = qt * 32;
    const int l15 = lane & 15, l4 = lane >> 4;

    // Q fragments: 32 q rows (mf) x 64 d (kf)
    bfx8 qa[2][2];
#pragma unroll
    for (int mf = 0; mf < 2; ++mf)
#pragma unroll
        for (int kf = 0; kf < 2; ++kf)
            qa[mf][kf] = *(const bfx8*)(qkv + (size_t)(b * 1024 + q0 + mf * 16 + l15) * 1536 + h * 64 + kf * 32 + l4 * 8);

    const int kbase = ks * 512 + kg * 256;
    f32x4 oacc[2][4] = {};
    for (int it = 0; it < 8; ++it) {
        const int k0 = kbase + it * 32;
        // issue all global loads up front; V is consumed ~2 barriers later (latency hidden)
        bfx8 kb[2][2], vb[4];
#pragma unroll
        for (int nf = 0; nf < 4; ++nf)
            vb[nf] = *(const bfx8*)(vt + (size_t)((b * 8 + h) * 64 + nf * 16 + l15) * 1024 + k0 + l4 * 8);
#pragma unroll
        for (int nf = 0; nf < 2; ++nf)
#pragma unroll
            for (int kf = 0; kf < 2; ++kf)
                kb[nf][kf] = *(const bfx8*)(qkv + (size_t)(b * 1024 + k0 + nf * 16 + l15) * 1536 + 512 + h * 64 + kf * 32 + l4 * 8);
        // QK^T: 32q x 32k
        f32x4 sacc[2][2] = {};
#pragma unroll
        for (int kf = 0; kf < 2; ++kf)
#pragma unroll
            for (int mf = 0; mf < 2; ++mf)
#pragma unroll
                for (int nf = 0; nf < 2; ++nf)
                    sacc[mf][nf] = __builtin_amdgcn_mfma_f32_16x16x32_bf16(qa[mf][kf], kb[nf][kf], sacc[mf][nf], 0, 0, 0);
#pragma unroll
        for (int mf = 0; mf < 2; ++mf)
#pragma unroll
            for (int nf = 0; nf < 2; ++nf)
#pragma unroll
                for (int r = 0; r < 4; ++r)
                    sS[((b * 2 + kg) * 32 + mf * 16 + l4 * 4 + r) * 33 + nf * 16 + l15] = sacc[mf][nf][r] * 0.125f;
        bar_lds();
        // batch-softmax: 2048 (kg,q,k) elems / 512 threads = 4 each
#pragma unroll
        for (int jj = 0; jj < 4; ++jj) {
            int e = jj * 512 + t;
            int kg2 = e >> 10, q = (e >> 5) & 31, k = e & 31;
            int base = (kg2 * 32 + q) * 33 + k;
            float s0v = sS[base], s1v = sS[base + 2112], s2v = sS[base + 4224], s3v = sS[base + 6336];
            float mx = fmaxf(fmaxf(s0v, s1v), fmaxf(s2v, s3v));
            float e0 = __expf(s0v - mx), e1 = __expf(s1v - mx);
            float e2 = __expf(s2v - mx), e3 = __expf(s3v - mx);
            float inv = frcp(e0 + e1 + e2 + e3);
            int sw = (q * 64 + k * 2) ^ ((q & 3) << 4);
            char* pb = (char*)sPb + kg2 * 2048 + sw;
            *(uint16_t*)(pb)         = f2bf(e0 * inv);
            *(uint16_t*)(pb + 4096)  = f2bf(e1 * inv);
            *(uint16_t*)(pb + 8192)  = f2bf(e2 * inv);
            *(uint16_t*)(pb + 12288) = f2bf(e3 * inv);
        }
        bar_lds();
        // PV: P(32q x 32k) @ V^T(32k x 64d); read matches write layout b*4096 + kg*2048
        bfx8 pa[2];
#pragma unroll
        for (int mf = 0; mf < 2; ++mf) {
            int row = mf * 16 + l15;
            pa[mf] = *(const bfx8*)((char*)sPb + (b * 2 + kg) * 2048 + ((row * 64 + l4 * 16) ^ ((row & 3) << 4)));
        }
#pragma unroll
        for (int mf = 0; mf < 2; ++mf)
#pragma unroll
            for (int nf = 0; nf < 4; ++nf)
                oacc[mf][nf] = __builtin_amdgcn_mfma_f32_16x16x32_bf16(pa[mf], vb[nf], oacc[mf][nf], 0, 0, 0);
    }
    // combine the two k-groups (sO aliases sS region; all LDS reads drained at barrier)
    bar_lds();
    if (kg == 1) {
#pragma unroll
        for (int mf = 0; mf < 2; ++mf)
#pragma unroll
            for (int nf = 0; nf < 4; ++nf)
#pragma unroll
                for (int r = 0; r < 4; ++r)
                    sO[(b * 32 + mf * 16 + l4 * 4 + r) * 64 + nf * 16 + l15] = oacc[mf][nf][r];
    }
    bar_lds();
    if (kg == 0) {
#pragma unroll
        for (int mf = 0; mf < 2; ++mf)
#pragma unroll
            for (int nf = 0; nf < 4; ++nf)
#pragma unroll
                for (int r = 0; r < 4; ++r) {
                    float v = oacc[mf][nf][r] + sO[(b * 32 + mf * 16 + l4 * 4 + r) * 64 + nf * 16 + l15];
                    o16[(size_t)(b * 1024 + q0 + mf * 16 + l4 * 4 + r) * 1024 + ks * 512 + h * 64 + nf * 16 + l15] = f2bf(v);
                }
    }
}

// ---------------- fused  ln_attn -> silu -> ln1  (one wave per row) ----------------
__global__ __launch_bounds__(64) void ln_fuse_k(const float* __restrict__ in,
    const float* __restrict__ g1, const float* __restrict__ b1,
    const float* __restrict__ g2, const float* __restrict__ b2,
    float* __restrict__ h32, uint16_t* __restrict__ h16)
{
    const int row = blockIdx.x, lane = threadIdx.x;
    const float* p = in + (size_t)row * 512 + lane * 8;
    f32x4 a = *(const f32x4*)p, bvec = *(const f32x4*)(p + 4);
    float x[8] = {a[0], a[1], a[2], a[3], bvec[0], bvec[1], bvec[2], bvec[3]};
    float sum = 0.f, sq = 0.f;
#pragma unroll
    for (int i = 0; i < 8; ++i) { sum += x[i]; sq += x[i] * x[i]; }
    for (int m = 32; m; m >>= 1) { sum += __shfl_xor(sum, m); sq += __shfl_xor(sq, m); }
    float mu = sum * (1.f / 512.f);
    float rs = rsqrtf(sq * (1.f / 512.f) - mu * mu + 1e-5f);
    float y[8]; float s2 = 0.f, q2 = 0.f;
#pragma unroll
    for (int i = 0; i < 8; ++i) {
        int c = lane * 8 + i;
        float v = (x[i] - mu) * rs * g1[c] + b1[c];
        v = v * sigmoidf_(v);
        y[i] = v; s2 += v; q2 += v * v;
    }
    for (int m = 32; m; m >>= 1) { s2 += __shfl_xor(s2, m); q2 += __shfl_xor(q2, m); }
    float mu2 = s2 * (1.f / 512.f);
    float rs2 = rsqrtf(q2 * (1.f / 512.f) - mu2 * mu2 + 1e-5f);
#pragma unroll
    for (int i = 0; i < 8; ++i) {
        int c = lane * 8 + i;
        float v = (y[i] - mu2) * rs2 * g2[c] + b2[c];
        h32[(size_t)row * 512 + c] = v;
        h16[(size_t)row * 512 + c] = f2bf(v);
    }
}

// ---------------- x16 = ln2(f + h) ----------------
__global__ __launch_bounds__(64) void ln_res_k(const float* __restrict__ f, const float* __restrict__ hres,
    const float* __restrict__ g, const float* __restrict__ bb, uint16_t* __restrict__ x16)
{
    const int row = blockIdx.x, lane = threadIdx.x;
    const size_t base = (size_t)row * 512 + lane * 8;
    f32x4 a = *(const f32x4*)(f + base), b2v = *(const f32x4*)(f + base + 4);
    f32x4 ha = *(const f32x4*)(hres + base), hb = *(const f32x4*)(hres + base + 4);
    float x[8] = {a[0] + ha[0], a[1] + ha[1], a[2] + ha[2], a[3] + ha[3],
                  b2v[0] + hb[0], b2v[1] + hb[1], b2v[2] + hb[2], b2v[3] + hb[3]};
    float sum = 0.f, sq = 0.f;
#pragma unroll
    for (int i = 0; i < 8; ++i) { sum += x[i]; sq += x[i] * x[i]; }
    for (int m = 32; m; m >>= 1) { sum += __shfl_xor(sum, m); sq += __shfl_xor(sq, m); }
    float mu = sum * (1.f / 512.f);
    float rs = rsqrtf(sq * (1.f / 512.f) - mu * mu + 1e-5f);
#pragma unroll
    for (int i = 0; i < 8; ++i) {
        int c = lane * 8 + i;
        float v = (x[i] - mu) * rs * g[c] + bb[c];
        x16[base + i] = f2bf(v);
    }
}

// ---------------- regression head: [T,512]bf16 @ [512,18] + b ----------------
__global__ __launch_bounds__(256) void reg_k(const uint16_t* __restrict__ x16, const float* __restrict__ W,
    const float* __restrict__ bb, float* __restrict__ out)
{
    const int gid = blockIdx.x * 256 + threadIdx.x;
    const int row = gid >> 3, kq = gid & 7;
    const uint16_t* xp = x16 + (size_t)row * 512 + kq * 64;
    float acc[18];
#pragma unroll
    for (int j = 0; j < 18; ++j) acc[j] = 0.f;
    for (int k0 = 0; k0 < 64; k0 += 8) {
        u16x8 xv = *(const u16x8*)(xp + k0);
#pragma unroll
        for (int kk = 0; kk < 8; ++kk) {
            const float* wr = W + (size_t)(kq * 64 + k0 + kk) * 18;
            f32x4 w0 = *(const f32x4*)(wr);
            f32x4 w1 = *(const f32x4*)(wr + 4);
            f32x4 w2 = *(const f32x4*)(wr + 8);
            f32x4 w3 = *(const f32x4*)(wr + 12);
            f32x2 w4 = *(const f32x2*)(wr + 16);
            float xs = bf2f(xv[kk]);
#pragma unroll
            for (int j = 0; j < 4; ++j) acc[j] += xs * w0[j];
#pragma unroll
            for (int j = 0; j < 4; ++j) acc[4 + j] += xs * w1[j];
#pragma unroll
            for (int j = 0; j < 4; ++j) acc[8 + j] += xs * w2[j];
#pragma unroll
            for (int j = 0; j < 4; ++j) acc[12 + j] += xs * w3[j];
            acc[16] += xs * w4[0];
            acc[17] += xs * w4[1];
        }
    }
#pragma unroll
    for (int j = 0; j < 18; ++j) {
        acc[j] += __shfl_xor(acc[j], 1);
        acc[j] += __shfl_xor(acc[j], 2);
        acc[j] += __shfl_xor(acc[j], 4);
    }
    if (kq == 0) {
#pragma unroll
        for (int j = 0; j < 18; ++j)
            out[(size_t)row * 18 + j] = acc[j] + bb[j];
    }
}

// ---------------- launch ----------------
extern "C" void kernel_launch(void* const* d_in, const int* in_sizes, int n_in,
                              void* d_out, int out_size, void* d_ws, size_t ws_size,
                              hipStream_t stream)
{
    const float* features = (const float*)d_in[0];
    const float* target   = (const float*)d_in[1];
    const float* emb_W    = (const float*)d_in[4];
    const float* emb_b    = (const float*)d_in[5];
    const float* station  = (const float*)d_in[6];
    const float* Wq   = (const float*)d_in[7];
    const float* Wk   = (const float*)d_in[8];
    const float* Wv   = (const float*)d_in[9];
    const float* Wo   = (const float*)d_in[10];
    const float* attn_b = (const float*)d_in[11];
    const float* lng  = (const float*)d_in[12];
    const float* lnb  = (const float*)d_in[13];
    const float* W1   = (const float*)d_in[14];
    const float* b1   = (const float*)d_in[15];
    const float* W2   = (const float*)d_in[16];
    const float* b2   = (const float*)d_in[17];
    const float* ln1g = (const float*)d_in[18];
    const float* ln1b = (const float*)d_in[19];
    const float* ln2g = (const float*)d_in[20];
    const float* ln2b = (const float*)d_in[21];
    const float* regW = (const float*)d_in[22];
    const float* regb = (const float*)d_in[23];
    float* out = (float*)d_out;

    const size_t NEEDED = 73531392;
    if (ws_size < NEEDED) return;   // fail visibly (output stays poisoned) rather than corrupt

    char* ws = (char*)d_ws;
    uint16_t* wt   = (uint16_t*)(ws);             // 19,005,440 B bf16 weight arena
    uint16_t* x16  = (uint16_t*)(ws + 19005440);  // 4 MB
    uint16_t* qkv  = (uint16_t*)(ws + 23199744);  // 12 MB
    uint16_t* vt   = (uint16_t*)(ws + 35782656);  // 4 MB
    uint16_t* o16  = (uint16_t*)(ws + 39976960);  // 8 MB  [4096][1024] split-O
    float*    t32  = (float*)(ws + 48365568);     // 8 MB
    float*    h32  = (float*)(ws + 56754176);     // 8 MB
    uint16_t* h16  = (uint16_t*)(ws + 65142784);  // 4 MB
    uint16_t* f16  = (uint16_t*)(ws + 69337088);  // 4 MB
    uint16_t* fm16 = (uint16_t*)(ws + 56754176);  // 1 MB, aliases h32 (dead until layer 0 ln_fuse)

    wconv_k<<<dim3(8, 8, 37), 256, 0, stream>>>(Wq, Wk, Wv, Wo, W1, W2, emb_W, wt);
    fmean_k<<<dim3(2048), 256, 0, stream>>>(features, fm16);
    gemm64<1, 0, 0, 0><<<dim3(8, 64), 256, 0, stream>>>(fm16, wt + 9437184u, emb_b, t32, 4096, 512, 128);
    station_k<<<dim3(4096), 256, 0, stream>>>(target, station, t32, x16);

    for (int l = 0; l < 6; ++l) {
        gemm128<<<dim3(12, 32), 256, 0, stream>>>(x16, wt + (size_t)l * 786432u, qkv, 1536, 512);
        vtrans_k<<<dim3(16, 32), 256, 0, stream>>>(qkv, vt);
        attn_k<<<dim3(512), 512, 0, stream>>>(qkv, vt, o16);
        gemm64<1, 0, 0, 1><<<dim3(8, 64), 256, 0, stream>>>(o16, wt + 4718592u + (size_t)l * 262144u, attn_b + l * 512, t32, 4096, 512, 1024);
        ln_fuse_k<<<dim3(4096), 64, 0, stream>>>(t32, lng + l * 512, lnb + l * 512, ln1g + l * 512, ln1b + l * 512, h32, h16);
        gemm64<1, 1, 1, 0><<<dim3(8, 64), 256, 0, stream>>>(h16, wt + 6291456u + (size_t)l * 262144u, b1 + l * 512, f16, 4096, 512, 512);
        gemm64<1, 0, 0, 0><<<dim3(8, 64), 256, 0, stream>>>(f16, wt + 7864320u + (size_t)l * 262144u, b2 + l * 512, t32, 4096, 512, 512);
        ln_res_k<<<dim3(4096), 64, 0, stream>>>(t32, h32, ln2g + l * 512, ln2b + l * 512, x16);
    }
    reg_k<<<dim3(128), 256, 0, stream>>>(x16, regW, regb, out);
}